// Round 7
// baseline (254.646 us; speedup 1.0000x reference)
//
#include <hip/hip_runtime.h>

typedef float v2f __attribute__((ext_vector_type(2)));

#define W 1024
#define H 1024
#define NB 16
#define TX 32
#define STEP 32             // output rows per step
#define NSTEP 4
#define YSEG (STEP * NSTEP) // 128 output rows per block (8 blocks cover H exactly)
#define BR 38               // LDS buffer rows = 6 halo + STEP
#define NTH 256
#define RSTRIDE (8 * TX)    // dwords per buffer row: 8 channels x 32 cols

// Horizontal 7-tap conv of the 8 SSIM product channels for one image row and
// 4 output cols, packed as 2x v2f with weight-pair table (V[m] broadcasts).
__device__ __forceinline__ void hconv_task(
    const float* __restrict__ p1, const float* __restrict__ p2,
    const float* __restrict__ p3, int gy, int gx0, bool xfast,
    const v2f* __restrict__ gp, float* __restrict__ dst /* &hbuf[row*RSTRIDE+c0] */)
{
    v2f accA[8], accB[8];   // j=(0,1), j=(2,3)
    #pragma unroll
    for (int ch = 0; ch < 8; ++ch) { accA[ch] = (v2f)0.0f; accB[ch] = (v2f)0.0f; }

    if ((gy >= 0) & (gy < H)) {
        const size_t rowoff = (size_t)gy * W;
        float V1[12], V2[12], V3[12];
        if (xfast) {
            const float* q1 = p1 + rowoff + gx0;
            const float* q2 = p2 + rowoff + gx0;
            const float* q3 = p3 + rowoff + gx0;
            *(float4*)&V1[0] = *(const float4*)(q1);
            *(float4*)&V1[4] = *(const float4*)(q1 + 4);
            *(float4*)&V1[8] = *(const float4*)(q1 + 8);
            *(float4*)&V2[0] = *(const float4*)(q2);
            *(float4*)&V2[4] = *(const float4*)(q2 + 4);
            *(float4*)&V2[8] = *(const float4*)(q2 + 8);
            *(float4*)&V3[0] = *(const float4*)(q3);
            *(float4*)&V3[4] = *(const float4*)(q3 + 4);
            *(float4*)&V3[8] = *(const float4*)(q3 + 8);
        } else {
            #pragma unroll
            for (int c = 0; c < 12; ++c) {
                const int x = gx0 + c;
                const bool ok = (x >= 0) & (x < W);
                const size_t off = rowoff + x;
                V1[c] = ok ? p1[off] : 0.0f;
                V2[c] = ok ? p2[off] : 0.0f;
                V3[c] = ok ? p3[off] : 0.0f;
            }
        }
        #pragma unroll
        for (int m = 1; m <= 8; ++m) {
            const v2f w = gp[m - 1];
            const float vA1 = V1[m], vA2 = V2[m], vA3 = V3[m];
            const float vB1 = V1[m + 2], vB2 = V2[m + 2], vB3 = V3[m + 2];
            v2f t;
            t = w * vA1; accA[0] += t; accA[3] += t * vA1; accA[6] += t * vA2; accA[7] += t * vA3;
            t = w * vA2; accA[1] += t; accA[4] += t * vA2;
            t = w * vA3; accA[2] += t; accA[5] += t * vA3;
            t = w * vB1; accB[0] += t; accB[3] += t * vB1; accB[6] += t * vB2; accB[7] += t * vB3;
            t = w * vB2; accB[1] += t; accB[4] += t * vB2;
            t = w * vB3; accB[2] += t; accB[5] += t * vB3;
        }
    }
    #pragma unroll
    for (int ch = 0; ch < 8; ++ch) {
        *(v2f*)(dst + ch * TX)     = accA[ch];
        *(v2f*)(dst + ch * TX + 2) = accB[ch];
    }
}

// Fused SSIM: each block covers a 32-col x 128-row segment in 4 steps of 32
// rows. The 6 halo h-rows are carried between steps by a static shift-copy
// (all LDS offsets compile-time constant). Per step both stages are perfect
// 1-task-per-thread.
__global__ __launch_bounds__(NTH, 4) void ssim_main(
    const float* __restrict__ img1, const float* __restrict__ img2,
    const float* __restrict__ img3, const float* __restrict__ win,
    float* __restrict__ partial)
{
    __shared__ __align__(16) float hbuf[BR * RSTRIDE];  // 38912 B
    __shared__ float wavesum[4];

    const int tid = threadIdx.x;
    const int x0  = blockIdx.x * TX;
    const int ys0 = blockIdx.y * YSEG;
    const size_t imoff = (size_t)blockIdx.z * (size_t)(W * H);
    const float* p1 = img1 + imoff;
    const float* p2 = img2 + imoff;
    const float* p3 = img3 + imoff;

    // Separable 1-D gaussian: g[j] = win[3][j] / sqrt(win[3][3])
    float g[7];
    {
        const float inv = 1.0f / sqrtf(win[24]);
        #pragma unroll
        for (int j = 0; j < 7; ++j) g[j] = win[21 + j] * inv;
    }
    // weight-pair table: out[j] = sum_m gp[m-1][j-?]*V[m]
    v2f gp[8];
    gp[0] = (v2f){g[0], 0.0f};
    #pragma unroll
    for (int m = 2; m <= 7; ++m) gp[m - 1] = (v2f){g[m - 1], g[m - 2]};
    gp[7] = (v2f){0.0f, g[6]};

    // Stage-B fixed geometry: one task per thread per step
    const int br  = tid >> 3;            // 0..31
    const int bc0 = (tid & 7) << 2;      // 0,4,...,28
    const int gx0 = x0 + bc0 - 4;
    const bool xfast = (gx0 >= 0) & (gx0 + 12 <= W);

    // Prime halo rows 0..5 (image h-rows ys0-3 .. ys0+2)
    if (tid < 48) {
        const int pr  = tid >> 3;        // 0..5
        const int pc0 = (tid & 7) << 2;
        const int pgx0 = x0 + pc0 - 4;
        const bool pxf = (pgx0 >= 0) & (pgx0 + 12 <= W);
        hconv_task(p1, p2, p3, ys0 - 3 + pr, pgx0, pxf, gp, &hbuf[pr * RSTRIDE + pc0]);
    }

    // Stage-C fixed geometry
    const int tx = tid & 31;
    const int r0 = (tid >> 5) << 2;      // 0,4,...,28 (output row group within step)

    float lsum = 0.0f;

    for (int s = 0; s < NSTEP; ++s) {
        // ---- Stage B: h-conv 32 new rows into buffer rows 6..37 ----
        hconv_task(p1, p2, p3, ys0 + s * STEP + 3 + br, gx0, xfast, gp,
                   &hbuf[(6 + br) * RSTRIDE + bc0]);
        __syncthreads();

        // ---- Stage C: vertical conv (4-tall), packed channel pairs ----
        v2f sv[4][4];
        #pragma unroll
        for (int cp = 0; cp < 4; ++cp)
            #pragma unroll
            for (int j = 0; j < 4; ++j) sv[cp][j] = (v2f)0.0f;

        int base = r0 * RSTRIDE + tx;
        #pragma unroll
        for (int dy = 0; dy < 10; ++dy) {
            v2f p[4];
            #pragma unroll
            for (int cp = 0; cp < 4; ++cp) {
                p[cp].x = hbuf[base + cp * 64];       // channel 2cp
                p[cp].y = hbuf[base + cp * 64 + 32];  // channel 2cp+1
            }
            #pragma unroll
            for (int j = 0; j < 4; ++j) {
                const int dd = dy - j;
                if (dd >= 0 && dd < 7) {
                    const float wg = g[dd];
                    #pragma unroll
                    for (int cp = 0; cp < 4; ++cp) sv[cp][j] += wg * p[cp];
                }
            }
            base += RSTRIDE;
        }
        #pragma unroll
        for (int j = 0; j < 4; ++j) {
            const float mu1 = sv[0][j].x, mu2 = sv[0][j].y;
            const float mu3 = sv[1][j].x, E11 = sv[1][j].y;
            const float E22 = sv[2][j].x, E33 = sv[2][j].y;
            const float E12 = sv[3][j].x, E13 = sv[3][j].y;
            const float sig1  = E11 - mu1 * mu1;
            const float sig2  = E22 - mu2 * mu2;
            const float sig3  = E33 - mu3 * mu3;
            const float sig12 = E12 - mu1 * mu2;
            const float sig13 = E13 - mu1 * mu3;
            const float C2 = 9.0e-4f;  // 0.03^2
            const float m12 = (2.0f * sig12 + C2) * __builtin_amdgcn_rcpf(sig1 + sig2 + C2);
            const float m13 = (2.0f * sig13 + C2) * __builtin_amdgcn_rcpf(sig1 + sig3 + C2);
            lsum += (mu2 > mu3) ? m12 : m13;
        }
        __syncthreads();

        // ---- shift-copy: buffer rows 32..37 -> 0..5 (next step's halo) ----
        if (s < NSTEP - 1) {
            const int co = tid * 6;      // 6 dwords per thread, 1536 total
            const v2f a = *(const v2f*)&hbuf[32 * RSTRIDE + co];
            const v2f b = *(const v2f*)&hbuf[32 * RSTRIDE + co + 2];
            const v2f c = *(const v2f*)&hbuf[32 * RSTRIDE + co + 4];
            *(v2f*)&hbuf[co]     = a;
            *(v2f*)&hbuf[co + 2] = b;
            *(v2f*)&hbuf[co + 4] = c;
            __syncthreads();
        }
    }

    // ---- Block reduction (deterministic) ----
    #pragma unroll
    for (int o = 32; o > 0; o >>= 1) lsum += __shfl_down(lsum, o, 64);
    if ((tid & 63) == 0) wavesum[tid >> 6] = lsum;
    __syncthreads();
    if (tid == 0) {
        const float t = (wavesum[0] + wavesum[1]) + (wavesum[2] + wavesum[3]);
        partial[((size_t)blockIdx.z * gridDim.y + blockIdx.y) * gridDim.x + blockIdx.x] = t;
    }
}

// Deterministic final reduction: one block, fixed summation order, f64 accum.
__global__ __launch_bounds__(256) void ssim_reduce(
    const float* __restrict__ partial, float* __restrict__ out, int n)
{
    __shared__ double sh[256];
    const int tid = threadIdx.x;
    double s = 0.0;
    for (int i = tid; i < n; i += 256) s += (double)partial[i];
    sh[tid] = s;
    __syncthreads();
    for (int o = 128; o > 0; o >>= 1) {
        if (tid < o) sh[tid] += sh[tid + o];
        __syncthreads();
    }
    if (tid == 0) out[0] = (float)(sh[0] / (double)((size_t)NB * W * H));
}

extern "C" void kernel_launch(void* const* d_in, const int* in_sizes, int n_in,
                              void* d_out, int out_size, void* d_ws, size_t ws_size,
                              hipStream_t stream) {
    const float* img1 = (const float*)d_in[0];
    const float* img2 = (const float*)d_in[1];
    const float* img3 = (const float*)d_in[2];
    const float* win  = (const float*)d_in[3];
    float* out = (float*)d_out;
    float* partial = (float*)d_ws;

    dim3 grid(W / TX, H / YSEG, NB);  // 32 x 8 x 16 = 4096 blocks
    ssim_main<<<grid, NTH, 0, stream>>>(img1, img2, img3, win, partial);

    const int nblk = (W / TX) * (H / YSEG) * NB;
    ssim_reduce<<<1, 256, 0, stream>>>(partial, out, nblk);
}

// Round 8
// 123.758 us; speedup vs baseline: 2.0576x; 2.0576x over previous
//
#include <hip/hip_runtime.h>

typedef float v2f __attribute__((ext_vector_type(2)));

#define W 1024
#define H 1024
#define NB 16
#define TX 32
#define TY 26               // output rows per block
#define HR 32               // h-conv rows per block = TY + 6
#define NTH 256
#define YBLK ((H + TY - 1) / TY)   // 40 (last block 10 rows OOB, guarded)
#define RSTRIDE (8 * TX)    // dwords per h-row: 8 channels x 32 cols

// Vertical conv (TALL outputs) + SSIM map for one column, from LDS.
template <int TALL>
__device__ __forceinline__ float vconv_ssim(
    const float* __restrict__ hbuf, int base, const float* __restrict__ g,
    int gy0 /* image row of output j=0 */)
{
    v2f sv[4][TALL];
    #pragma unroll
    for (int cp = 0; cp < 4; ++cp)
        #pragma unroll
        for (int j = 0; j < TALL; ++j) sv[cp][j] = (v2f)0.0f;

    #pragma unroll
    for (int dy = 0; dy < TALL + 6; ++dy) {
        v2f p[4];
        #pragma unroll
        for (int cp = 0; cp < 4; ++cp) {
            p[cp].x = hbuf[base + cp * 64];       // channel 2cp
            p[cp].y = hbuf[base + cp * 64 + 32];  // channel 2cp+1
        }
        #pragma unroll
        for (int j = 0; j < TALL; ++j) {
            const int dd = dy - j;
            if (dd >= 0 && dd < 7) {
                const float wg = g[dd];
                #pragma unroll
                for (int cp = 0; cp < 4; ++cp) sv[cp][j] += wg * p[cp];
            }
        }
        base += RSTRIDE;
    }

    float lsum = 0.0f;
    #pragma unroll
    for (int j = 0; j < TALL; ++j) {
        if (gy0 + j < H) {
            const float mu1 = sv[0][j].x, mu2 = sv[0][j].y;
            const float mu3 = sv[1][j].x, E11 = sv[1][j].y;
            const float E22 = sv[2][j].x, E33 = sv[2][j].y;
            const float E12 = sv[3][j].x, E13 = sv[3][j].y;
            const float sig1  = E11 - mu1 * mu1;
            const float sig2  = E22 - mu2 * mu2;
            const float sig3  = E33 - mu3 * mu3;
            const float sig12 = E12 - mu1 * mu2;
            const float sig13 = E13 - mu1 * mu3;
            const float C2 = 9.0e-4f;  // 0.03^2
            const float m12 = (2.0f * sig12 + C2) * __builtin_amdgcn_rcpf(sig1 + sig2 + C2);
            const float m13 = (2.0f * sig13 + C2) * __builtin_amdgcn_rcpf(sig1 + sig3 + C2);
            lsum += (mu2 > mu3) ? m12 : m13;
        }
    }
    return lsum;
}

// Fused SSIM, packed-FP32, one-shot per block (no persistent loop state).
//   Stage B: 256 tasks = 32 h-rows x 8 col-groups, one per thread (1:1).
//   Stage C: waves 0-2: 3-tall columns (rows 0..17); wave 3: 4-tall (18..25).
//   LDS exactly 32 KB -> 5 blocks/CU; launch_bounds(256,5).
__global__ __launch_bounds__(NTH, 5) void ssim_main(
    const float* __restrict__ img1, const float* __restrict__ img2,
    const float* __restrict__ img3, const float* __restrict__ win,
    float* __restrict__ partial)
{
    __shared__ __align__(16) float hbuf[HR * RSTRIDE];  // 32768 B exactly

    const int tid = threadIdx.x;
    const int x0  = blockIdx.x * TX;
    const int ys0 = blockIdx.y * TY;
    const size_t imoff = (size_t)blockIdx.z * (size_t)(W * H);
    const float* p1 = img1 + imoff;
    const float* p2 = img2 + imoff;
    const float* p3 = img3 + imoff;

    // Separable 1-D gaussian: g[j] = win[3][j] / sqrt(win[3][3])
    float g[7];
    {
        const float inv = 1.0f / sqrtf(win[24]);
        #pragma unroll
        for (int j = 0; j < 7; ++j) g[j] = win[21 + j] * inv;
    }

    // ---- Stage B: horizontal conv, global -> LDS (1 task per thread) ----
    {
        const int br  = tid >> 3;            // 0..31  h-row within block
        const int bc0 = (tid & 7) << 2;      // 0,4,...,28
        const int gy  = ys0 + br - 3;
        const int gx0 = x0 + bc0 - 4;
        const bool xfast = (gx0 >= 0) & (gx0 + 12 <= W);

        v2f accA[8], accB[8];                // j=(0,1) and j=(2,3)
        #pragma unroll
        for (int ch = 0; ch < 8; ++ch) { accA[ch] = (v2f)0.0f; accB[ch] = (v2f)0.0f; }

        if ((gy >= 0) & (gy < H)) {
            const size_t rowoff = (size_t)gy * W;
            float V1[12], V2[12], V3[12];
            if (xfast) {
                const float* q1 = p1 + rowoff + gx0;
                const float* q2 = p2 + rowoff + gx0;
                const float* q3 = p3 + rowoff + gx0;
                *(float4*)&V1[0] = *(const float4*)(q1);
                *(float4*)&V1[4] = *(const float4*)(q1 + 4);
                *(float4*)&V1[8] = *(const float4*)(q1 + 8);
                *(float4*)&V2[0] = *(const float4*)(q2);
                *(float4*)&V2[4] = *(const float4*)(q2 + 4);
                *(float4*)&V2[8] = *(const float4*)(q2 + 8);
                *(float4*)&V3[0] = *(const float4*)(q3);
                *(float4*)&V3[4] = *(const float4*)(q3 + 4);
                *(float4*)&V3[8] = *(const float4*)(q3 + 8);
            } else {
                #pragma unroll
                for (int c = 0; c < 12; ++c) {
                    const int x = gx0 + c;
                    const bool ok = (x >= 0) & (x < W);
                    const size_t off = rowoff + x;
                    V1[c] = ok ? p1[off] : 0.0f;
                    V2[c] = ok ? p2[off] : 0.0f;
                    V3[c] = ok ? p3[off] : 0.0f;
                }
            }

            // weight-pair table: out[j] = sum_m gp-style, V[m] broadcasts
            v2f gp[8];
            gp[0] = (v2f){g[0], 0.0f};
            #pragma unroll
            for (int m = 2; m <= 7; ++m) gp[m - 1] = (v2f){g[m - 1], g[m - 2]};
            gp[7] = (v2f){0.0f, g[6]};

            #pragma unroll
            for (int m = 1; m <= 8; ++m) {
                const v2f w = gp[m - 1];
                const float vA1 = V1[m], vA2 = V2[m], vA3 = V3[m];
                const float vB1 = V1[m + 2], vB2 = V2[m + 2], vB3 = V3[m + 2];
                v2f t;
                t = w * vA1; accA[0] += t; accA[3] += t * vA1; accA[6] += t * vA2; accA[7] += t * vA3;
                t = w * vA2; accA[1] += t; accA[4] += t * vA2;
                t = w * vA3; accA[2] += t; accA[5] += t * vA3;
                t = w * vB1; accB[0] += t; accB[3] += t * vB1; accB[6] += t * vB2; accB[7] += t * vB3;
                t = w * vB2; accB[1] += t; accB[4] += t * vB2;
                t = w * vB3; accB[2] += t; accB[5] += t * vB3;
            }
        }
        const int wbase = br * RSTRIDE + bc0;
        #pragma unroll
        for (int ch = 0; ch < 8; ++ch) {
            *(v2f*)&hbuf[wbase + ch * TX]     = accA[ch];
            *(v2f*)&hbuf[wbase + ch * TX + 2] = accB[ch];
        }
    }
    __syncthreads();

    // ---- Stage C: vertical conv + SSIM (3-tall on waves 0-2, 4-tall wave 3) ----
    const int tx = tid & 31;
    float lsum;
    if (tid < 192) {
        const int r0 = (tid >> 5) * 3;           // 0,3,...,15
        lsum = vconv_ssim<3>(hbuf, r0 * RSTRIDE + tx, g, ys0 + r0);
    } else {
        const int r0 = 18 + (((tid >> 5) - 6) << 2);  // 18, 22
        lsum = vconv_ssim<4>(hbuf, r0 * RSTRIDE + tx, g, ys0 + r0);
    }

    // ---- Block reduction (deterministic); alias wavesum onto hbuf ----
    #pragma unroll
    for (int o = 32; o > 0; o >>= 1) lsum += __shfl_down(lsum, o, 64);
    __syncthreads();                      // all hbuf reads done before aliasing
    float* wavesum = hbuf;
    if ((tid & 63) == 0) wavesum[tid >> 6] = lsum;
    __syncthreads();
    if (tid == 0) {
        const float t = (wavesum[0] + wavesum[1]) + (wavesum[2] + wavesum[3]);
        partial[((size_t)blockIdx.z * gridDim.y + blockIdx.y) * gridDim.x + blockIdx.x] = t;
    }
}

// Deterministic final reduction: one block, fixed summation order, f64 accum.
__global__ __launch_bounds__(256) void ssim_reduce(
    const float* __restrict__ partial, float* __restrict__ out, int n)
{
    __shared__ double sh[256];
    const int tid = threadIdx.x;
    double s = 0.0;
    for (int i = tid; i < n; i += 256) s += (double)partial[i];
    sh[tid] = s;
    __syncthreads();
    for (int o = 128; o > 0; o >>= 1) {
        if (tid < o) sh[tid] += sh[tid + o];
        __syncthreads();
    }
    if (tid == 0) out[0] = (float)(sh[0] / (double)((size_t)NB * W * H));
}

extern "C" void kernel_launch(void* const* d_in, const int* in_sizes, int n_in,
                              void* d_out, int out_size, void* d_ws, size_t ws_size,
                              hipStream_t stream) {
    const float* img1 = (const float*)d_in[0];
    const float* img2 = (const float*)d_in[1];
    const float* img3 = (const float*)d_in[2];
    const float* win  = (const float*)d_in[3];
    float* out = (float*)d_out;
    float* partial = (float*)d_ws;

    dim3 grid(W / TX, YBLK, NB);  // 32 x 40 x 16 = 20480 blocks
    ssim_main<<<grid, NTH, 0, stream>>>(img1, img2, img3, win, partial);

    const int nblk = (W / TX) * YBLK * NB;
    ssim_reduce<<<1, 256, 0, stream>>>(partial, out, nblk);
}